// Round 6
// baseline (579.778 us; speedup 1.0000x reference)
//
#include <hip/hip_runtime.h>
#include <cstdint>
#include <cstddef>

typedef __bf16 bf16;
typedef __bf16 bf16x8 __attribute__((ext_vector_type(8)));
typedef float floatx4 __attribute__((ext_vector_type(4)));
typedef float floatx8 __attribute__((ext_vector_type(8)));

constexpr int Bb = 4, Ll = 4096, Dd = 1024;
constexpr int M  = Bb * Ll;          // 16384 rows
constexpr int NC = 64, CT = 64;      // chunks per sequence, chunk length

// ---------------- mix GEMM: C[m,n] = sum_k mix(A)[m,k] * W[n,k] ----------------
// A, W, mixv f32; MFMA runs bf16 (converted during LDS staging).
// ACT: 0 = f32 out, 1 = sigmoid bf16 out, 2 = bf16 out
template <int ACT>
__global__ __launch_bounds__(256) void gemm_xmix(
    const float* __restrict__ A, const float* __restrict__ mixv,
    const float* __restrict__ W, void* __restrict__ Cout)
{
  __shared__ __align__(16) bf16 As[128 * 32];
  __shared__ __align__(16) bf16 Bs[128 * 32];
  const int tid  = threadIdx.x;
  const int lane = tid & 63;
  const int w    = tid >> 6;
  const int wm   = (w >> 1) * 64, wn = (w & 1) * 64;
  const int fr   = lane & 15;
  const int fo   = (lane >> 4) * 8;
  const int m0   = blockIdx.y * 128, n0 = blockIdx.x * 128;

  floatx4 acc[4][4];
  #pragma unroll
  for (int i = 0; i < 4; ++i)
    #pragma unroll
    for (int j = 0; j < 4; ++j)
      acc[i][j] = (floatx4)(0.0f);

  for (int k0 = 0; k0 < Dd; k0 += 32) {
    #pragma unroll
    for (int r2 = 0; r2 < 2; ++r2) {
      int u = r2 * 256 + tid;              // 0..511; 8 elems each
      int row = u >> 2, c8 = (u & 3) * 8;
      int m = m0 + row;
      const float* ap = A + (size_t)m * Dd + k0 + c8;
      floatx8 xc = *(const floatx8*)ap;
      floatx8 xp;
      if (m & (Ll - 1)) xp = *(const floatx8*)(ap - Dd);
      else              xp = (floatx8)(0.0f);
      floatx8 tm = *(const floatx8*)(mixv + k0 + c8);
      bf16x8 ao;
      #pragma unroll
      for (int j = 0; j < 8; ++j)
        ao[j] = (bf16)(xc[j] * tm[j] + xp[j] * (1.0f - tm[j]));
      *(bf16x8*)(As + (size_t)u * 8) = ao;

      floatx8 wb = *(const floatx8*)(W + (size_t)(n0 + row) * Dd + k0 + c8);
      bf16x8 bo;
      #pragma unroll
      for (int j = 0; j < 8; ++j) bo[j] = (bf16)wb[j];
      *(bf16x8*)(Bs + (size_t)u * 8) = bo;
    }
    __syncthreads();
    bf16x8 af[4], bfv[4];
    #pragma unroll
    for (int i = 0; i < 4; ++i) af[i]  = *(const bf16x8*)(As + (wm + i * 16 + fr) * 32 + fo);
    #pragma unroll
    for (int j = 0; j < 4; ++j) bfv[j] = *(const bf16x8*)(Bs + (wn + j * 16 + fr) * 32 + fo);
    #pragma unroll
    for (int i = 0; i < 4; ++i)
      #pragma unroll
      for (int j = 0; j < 4; ++j)
        acc[i][j] = __builtin_amdgcn_mfma_f32_16x16x32_bf16(af[i], bfv[j], acc[i][j], 0, 0, 0);
    __syncthreads();
  }

  // epilogue: C/D layout col = lane&15, row = (lane>>4)*4 + reg
  #pragma unroll
  for (int i = 0; i < 4; ++i) {
    int rbase = m0 + wm + i * 16 + (lane >> 4) * 4;
    #pragma unroll
    for (int j = 0; j < 4; ++j) {
      int col = n0 + wn + j * 16 + (lane & 15);
      #pragma unroll
      for (int r = 0; r < 4; ++r) {
        float v = acc[i][j][r];
        size_t off = (size_t)(rbase + r) * Dd + col;
        if (ACT == 0)      ((float*)Cout)[off] = v;
        else if (ACT == 1) ((bf16*)Cout)[off]  = (bf16)(1.0f / (1.0f + __expf(-v)));
        else               ((bf16*)Cout)[off]  = (bf16)v;
      }
    }
  }
}

// ---------------- output GEMM: A bf16 (y), W f32, C written as F32 (d_out is f32!) ----
__global__ __launch_bounds__(256) void gemm_y(
    const bf16* __restrict__ A, const float* __restrict__ W, float* __restrict__ Cout)
{
  __shared__ __align__(16) bf16 As[128 * 32];
  __shared__ __align__(16) bf16 Bs[128 * 32];
  const int tid  = threadIdx.x;
  const int lane = tid & 63;
  const int w    = tid >> 6;
  const int wm   = (w >> 1) * 64, wn = (w & 1) * 64;
  const int fr   = lane & 15;
  const int fo   = (lane >> 4) * 8;
  const int m0   = blockIdx.y * 128, n0 = blockIdx.x * 128;

  floatx4 acc[4][4];
  #pragma unroll
  for (int i = 0; i < 4; ++i)
    #pragma unroll
    for (int j = 0; j < 4; ++j)
      acc[i][j] = (floatx4)(0.0f);

  for (int k0 = 0; k0 < Dd; k0 += 32) {
    #pragma unroll
    for (int r2 = 0; r2 < 2; ++r2) {
      int u = r2 * 256 + tid;
      int row = u >> 2, c8 = (u & 3) * 8;
      *(bf16x8*)(As + (size_t)u * 8) =
          *(const bf16x8*)(A + (size_t)(m0 + row) * Dd + k0 + c8);
      floatx8 wb = *(const floatx8*)(W + (size_t)(n0 + row) * Dd + k0 + c8);
      bf16x8 bo;
      #pragma unroll
      for (int j = 0; j < 8; ++j) bo[j] = (bf16)wb[j];
      *(bf16x8*)(Bs + (size_t)u * 8) = bo;
    }
    __syncthreads();
    bf16x8 af[4], bfv[4];
    #pragma unroll
    for (int i = 0; i < 4; ++i) af[i]  = *(const bf16x8*)(As + (wm + i * 16 + fr) * 32 + fo);
    #pragma unroll
    for (int j = 0; j < 4; ++j) bfv[j] = *(const bf16x8*)(Bs + (wn + j * 16 + fr) * 32 + fo);
    #pragma unroll
    for (int i = 0; i < 4; ++i)
      #pragma unroll
      for (int j = 0; j < 4; ++j)
        acc[i][j] = __builtin_amdgcn_mfma_f32_16x16x32_bf16(af[i], bfv[j], acc[i][j], 0, 0, 0);
    __syncthreads();
  }

  #pragma unroll
  for (int i = 0; i < 4; ++i) {
    int rbase = m0 + wm + i * 16 + (lane >> 4) * 4;
    #pragma unroll
    for (int j = 0; j < 4; ++j) {
      int col = n0 + wn + j * 16 + (lane & 15);
      #pragma unroll
      for (int r = 0; r < 4; ++r)
        Cout[(size_t)(rbase + r) * Dd + col] = acc[i][j][r];   // f32 store
    }
  }
}

// ---------------- WKV chunked scan ----------------
__global__ __launch_bounds__(256) void scan_partial(
    const float* __restrict__ k, const bf16* __restrict__ v,
    const float* __restrict__ td, float* __restrict__ Pa, float* __restrict__ Pb)
{
  int d = blockIdx.x * 256 + threadIdx.x;
  int b = blockIdx.y, c = blockIdx.z;
  float decay = __expf(-__expf(td[d]));
  size_t base = ((size_t)(b * Ll + c * CT)) * Dd + d;
  float pa = 0.0f, pb = 0.0f;
  #pragma unroll 4
  for (int t = 0; t < CT; ++t) {
    size_t idx = base + (size_t)t * Dd;
    float ek = __expf(k[idx]);
    pa = decay * pa + ek * (float)v[idx];
    pb = decay * pb + ek;
  }
  size_t o = ((size_t)(b * NC + c)) * Dd + d;
  Pa[o] = pa; Pb[o] = pb;
}

__global__ __launch_bounds__(256) void scan_combine(
    const float* __restrict__ td, const float* __restrict__ Pa, const float* __restrict__ Pb,
    float* __restrict__ A0, float* __restrict__ B0)
{
  int d = blockIdx.x * 256 + threadIdx.x;
  int b = blockIdx.y;
  float dT = __expf(-__expf(td[d]) * (float)CT);   // decay^CT
  float a = 0.0f, bb = 0.0f;
  for (int c = 0; c < NC; ++c) {
    size_t o = ((size_t)(b * NC + c)) * Dd + d;
    A0[o] = a; B0[o] = bb;
    a  = dT * a  + Pa[o];
    bb = dT * bb + Pb[o];
  }
}

// Writes y IN-PLACE over v (thread-local read-before-write at identical index).
__global__ __launch_bounds__(256) void scan_final(
    const float* __restrict__ k, bf16* __restrict__ vy, const bf16* __restrict__ r,
    const float* __restrict__ td, const float* __restrict__ tf,
    const float* __restrict__ A0, const float* __restrict__ B0)
{
  int d = blockIdx.x * 256 + threadIdx.x;
  int b = blockIdx.y, c = blockIdx.z;
  float decay = __expf(-__expf(td[d]));
  float u     = tf[d];
  size_t o = ((size_t)(b * NC + c)) * Dd + d;
  float a = A0[o], bb = B0[o];
  size_t base = ((size_t)(b * Ll + c * CT)) * Dd + d;
  for (int t = 0; t < CT; ++t) {
    size_t idx = base + (size_t)t * Dd;
    float kk = k[idx];
    float vv = (float)vy[idx];
    float eku = __expf(u + kk);
    float wkv = (a + eku * vv) / fmaxf(bb + eku, 1e-6f);
    vy[idx] = (bf16)((float)r[idx] * wkv);
    float ek = __expf(kk);
    a  = decay * a  + ek * vv;
    bb = decay * bb + ek;
  }
}

// ---------------- launch ----------------
extern "C" void kernel_launch(void* const* d_in, const int* in_sizes, int n_in,
                              void* d_out, int out_size, void* d_ws, size_t ws_size,
                              hipStream_t stream)
{
  const float* x  = (const float*)d_in[0];
  const float* td = (const float*)d_in[1];
  const float* tf = (const float*)d_in[2];
  const float* mk = (const float*)d_in[3];
  const float* mv = (const float*)d_in[4];
  const float* mr = (const float*)d_in[5];
  const float* Wk = (const float*)d_in[6];
  const float* Wv = (const float*)d_in[7];
  const float* Wr = (const float*)d_in[8];
  const float* Wo = (const float*)d_in[9];
  float* out = (float*)d_out;    // OUTPUT IS F32 (reference returns float32)

  // Workspace: k(f32, 64 MiB) + v/y(bf16, 32 MiB) + partials(4 MiB) = 100 MiB (fits).
  char* ws = (char*)d_ws;
  const size_t S4 = (size_t)M * Dd * sizeof(float);
  const size_t S2 = (size_t)M * Dd * sizeof(bf16);
  const size_t SP = (size_t)Bb * NC * Dd;
  float* kk = (float*)(ws);
  bf16*  vv = (bf16*)(ws + S4);
  float* Pa = (float*)(ws + S4 + S2);
  float* Pb = Pa + SP;
  float* A0 = Pb + SP;
  float* B0 = A0 + SP;
  // sigmoid(r) parks as bf16 in d_out (67 MB f32 buffer; first 33.5 MB used);
  // consumed by scan_final, then gemm_y overwrites d_out with the real f32 output.
  bf16* rr = (bf16*)d_out;

  dim3 gg(Dd / 128, M / 128);
  gemm_xmix<0><<<gg, 256, 0, stream>>>(x, mk, Wk, kk);   // k  (f32)
  gemm_xmix<2><<<gg, 256, 0, stream>>>(x, mv, Wv, vv);   // v  (bf16)
  gemm_xmix<1><<<gg, 256, 0, stream>>>(x, mr, Wr, rr);   // r  (sigmoid bf16) -> d_out

  scan_partial<<<dim3(Dd / 256, Bb, NC), 256, 0, stream>>>(kk, vv, td, Pa, Pb);
  scan_combine<<<dim3(Dd / 256, Bb), 256, 0, stream>>>(td, Pa, Pb, A0, B0);
  scan_final  <<<dim3(Dd / 256, Bb, NC), 256, 0, stream>>>(kk, vv, rr, td, tf, A0, B0);

  gemm_y<<<gg, 256, 0, stream>>>(vv, Wo, out);           // y·Wo -> d_out (f32)
}

// Round 7
// 505.624 us; speedup vs baseline: 1.1467x; 1.1467x over previous
//
#include <hip/hip_runtime.h>
#include <cstdint>
#include <cstddef>

typedef __bf16 bf16;
typedef __bf16 bf16x8 __attribute__((ext_vector_type(8)));
typedef float floatx4 __attribute__((ext_vector_type(4)));
typedef float floatx8 __attribute__((ext_vector_type(8)));
typedef unsigned int u32;

constexpr int Bb = 4, Ll = 4096, Dd = 1024;
constexpr int M  = Bb * Ll;          // 16384 rows
constexpr int NC = 64, CT = 64;      // chunks per sequence, chunk length

// async 16B global->LDS (the m97 ladder move; width=16 emits global_load_lds_dwordx4)
typedef const __attribute__((address_space(1))) u32 glb_u32;
typedef __attribute__((address_space(3))) u32 lds_u32;
__device__ __forceinline__ void gld16(const bf16* g, bf16* l) {
  __builtin_amdgcn_global_load_lds((glb_u32*)g, (lds_u32*)l, 16, 0, 0);
}

// ---------------- prep: token-shift mix, f32 x -> bf16 mixed arrays ----------------
__global__ __launch_bounds__(256) void prep2(
    const float* __restrict__ x, const float* __restrict__ ma, const float* __restrict__ mb,
    bf16* __restrict__ oa, bf16* __restrict__ ob)
{
  size_t base = ((size_t)blockIdx.x * 256 + threadIdx.x) * 8;
  int d = (int)(base & (size_t)(Dd - 1));
  int l = (int)((base / Dd) & (size_t)(Ll - 1));
  floatx8 xc = *(const floatx8*)(x + base);
  floatx8 xp = l ? *(const floatx8*)(x + base - Dd) : (floatx8)(0.0f);
  floatx8 a = *(const floatx8*)(ma + d);
  floatx8 b = *(const floatx8*)(mb + d);
  bf16x8 ra, rb;
  #pragma unroll
  for (int j = 0; j < 8; ++j) {
    ra[j] = (bf16)(xc[j] * a[j] + xp[j] * (1.0f - a[j]));
    rb[j] = (bf16)(xc[j] * b[j] + xp[j] * (1.0f - b[j]));
  }
  *(bf16x8*)(oa + base) = ra;
  *(bf16x8*)(ob + base) = rb;
}

__global__ __launch_bounds__(256) void prep1(
    const float* __restrict__ x, const float* __restrict__ ma, bf16* __restrict__ oa)
{
  size_t base = ((size_t)blockIdx.x * 256 + threadIdx.x) * 8;
  int d = (int)(base & (size_t)(Dd - 1));
  int l = (int)((base / Dd) & (size_t)(Ll - 1));
  floatx8 xc = *(const floatx8*)(x + base);
  floatx8 xp = l ? *(const floatx8*)(x + base - Dd) : (floatx8)(0.0f);
  floatx8 a = *(const floatx8*)(ma + d);
  bf16x8 ra;
  #pragma unroll
  for (int j = 0; j < 8; ++j)
    ra[j] = (bf16)(xc[j] * a[j] + xp[j] * (1.0f - a[j]));
  *(bf16x8*)(oa + base) = ra;
}

// ---------------- GEMM: C[m,n] = sum_k A[m,k]*W[n,k]; A bf16 (async DMA), W f32 ----
// ACT: 0 = f32 out, 1 = sigmoid bf16 out, 2 = bf16 out
template <int ACT>
__global__ __launch_bounds__(256) void gemm_a16(
    const bf16* __restrict__ A, const float* __restrict__ W, void* __restrict__ Cout)
{
  __shared__ __align__(16) bf16 As[128 * 32];
  __shared__ __align__(16) bf16 Bs[128 * 32];
  const int tid  = threadIdx.x;
  const int lane = tid & 63;
  const int w    = tid >> 6;
  const int wm   = (w >> 1) * 64, wn = (w & 1) * 64;
  const int fr   = lane & 15;
  const int fo   = (lane >> 4) * 8;
  const int m0   = blockIdx.y * 128, n0 = blockIdx.x * 128;

  const int u0 = tid, u1 = tid + 256;          // 16B staging units
  const int r0 = u0 >> 2, c0 = (u0 & 3) * 8;
  const int r1 = u1 >> 2, c1 = (u1 & 3) * 8;

  floatx4 acc[4][4];
  #pragma unroll
  for (int i = 0; i < 4; ++i)
    #pragma unroll
    for (int j = 0; j < 4; ++j)
      acc[i][j] = (floatx4)(0.0f);

  for (int k0 = 0; k0 < Dd; k0 += 32) {
    // A tile: pure async DMA, no VALU round-trip
    gld16(A + (size_t)(m0 + r0) * Dd + k0 + c0, As + (size_t)u0 * 8);
    gld16(A + (size_t)(m0 + r1) * Dd + k0 + c1, As + (size_t)u1 * 8);
    // B tile: f32 load + convert (W is small; stays hot in L2)
    floatx8 w0 = *(const floatx8*)(W + (size_t)(n0 + r0) * Dd + k0 + c0);
    floatx8 w1 = *(const floatx8*)(W + (size_t)(n0 + r1) * Dd + k0 + c1);
    bf16x8 b0, b1;
    #pragma unroll
    for (int j = 0; j < 8; ++j) { b0[j] = (bf16)w0[j]; b1[j] = (bf16)w1[j]; }
    *(bf16x8*)(Bs + (size_t)u0 * 8) = b0;
    *(bf16x8*)(Bs + (size_t)u1 * 8) = b1;
    __syncthreads();   // drains vmcnt (async LDS DMA) + lgkmcnt

    bf16x8 af[4], bfv[4];
    #pragma unroll
    for (int i = 0; i < 4; ++i) af[i]  = *(const bf16x8*)(As + (wm + i * 16 + fr) * 32 + fo);
    #pragma unroll
    for (int j = 0; j < 4; ++j) bfv[j] = *(const bf16x8*)(Bs + (wn + j * 16 + fr) * 32 + fo);
    #pragma unroll
    for (int i = 0; i < 4; ++i)
      #pragma unroll
      for (int j = 0; j < 4; ++j)
        acc[i][j] = __builtin_amdgcn_mfma_f32_16x16x32_bf16(af[i], bfv[j], acc[i][j], 0, 0, 0);
    __syncthreads();
  }

  // epilogue: C/D layout col = lane&15, row = (lane>>4)*4 + reg  (verified R4≡R5)
  #pragma unroll
  for (int i = 0; i < 4; ++i) {
    int rbase = m0 + wm + i * 16 + (lane >> 4) * 4;
    #pragma unroll
    for (int j = 0; j < 4; ++j) {
      int col = n0 + wn + j * 16 + (lane & 15);
      #pragma unroll
      for (int r = 0; r < 4; ++r) {
        float v = acc[i][j][r];
        size_t off = (size_t)(rbase + r) * Dd + col;
        if (ACT == 0)      ((float*)Cout)[off] = v;
        else if (ACT == 1) ((bf16*)Cout)[off]  = (bf16)(1.0f / (1.0f + __expf(-v)));
        else               ((bf16*)Cout)[off]  = (bf16)v;
      }
    }
  }
}

// ---------------- WKV chunked scan (k, v now bf16) ----------------
__global__ __launch_bounds__(256) void scan_partial(
    const bf16* __restrict__ k, const bf16* __restrict__ v,
    const float* __restrict__ td, float* __restrict__ Pa, float* __restrict__ Pb)
{
  int d = blockIdx.x * 256 + threadIdx.x;
  int b = blockIdx.y, c = blockIdx.z;
  float decay = __expf(-__expf(td[d]));
  size_t base = ((size_t)(b * Ll + c * CT)) * Dd + d;
  float pa = 0.0f, pb = 0.0f;
  #pragma unroll 4
  for (int t = 0; t < CT; ++t) {
    size_t idx = base + (size_t)t * Dd;
    float ek = __expf((float)k[idx]);
    pa = decay * pa + ek * (float)v[idx];
    pb = decay * pb + ek;
  }
  size_t o = ((size_t)(b * NC + c)) * Dd + d;
  Pa[o] = pa; Pb[o] = pb;
}

__global__ __launch_bounds__(256) void scan_combine(
    const float* __restrict__ td, const float* __restrict__ Pa, const float* __restrict__ Pb,
    float* __restrict__ A0, float* __restrict__ B0)
{
  int d = blockIdx.x * 256 + threadIdx.x;
  int b = blockIdx.y;
  float dT = __expf(-__expf(td[d]) * (float)CT);   // decay^CT
  float a = 0.0f, bb = 0.0f;
  for (int c = 0; c < NC; ++c) {
    size_t o = ((size_t)(b * NC + c)) * Dd + d;
    A0[o] = a; B0[o] = bb;
    a  = dT * a  + Pa[o];
    bb = dT * bb + Pb[o];
  }
}

// y written IN-PLACE over v (thread-local read-before-write at identical index)
__global__ __launch_bounds__(256) void scan_final(
    const bf16* __restrict__ k, bf16* __restrict__ vy, const bf16* __restrict__ r,
    const float* __restrict__ td, const float* __restrict__ tf,
    const float* __restrict__ A0, const float* __restrict__ B0)
{
  int d = blockIdx.x * 256 + threadIdx.x;
  int b = blockIdx.y, c = blockIdx.z;
  float decay = __expf(-__expf(td[d]));
  float u     = tf[d];
  size_t o = ((size_t)(b * NC + c)) * Dd + d;
  float a = A0[o], bb = B0[o];
  size_t base = ((size_t)(b * Ll + c * CT)) * Dd + d;
  for (int t = 0; t < CT; ++t) {
    size_t idx = base + (size_t)t * Dd;
    float kk = (float)k[idx];
    float vv = (float)vy[idx];
    float eku = __expf(u + kk);
    float wkv = (a + eku * vv) / fmaxf(bb + eku, 1e-6f);
    vy[idx] = (bf16)((float)r[idx] * wkv);
    float ek = __expf(kk);
    a  = decay * a  + ek * vv;
    bb = decay * bb + ek;
  }
}

// ---------------- launch ----------------
extern "C" void kernel_launch(void* const* d_in, const int* in_sizes, int n_in,
                              void* d_out, int out_size, void* d_ws, size_t ws_size,
                              hipStream_t stream)
{
  const float* x  = (const float*)d_in[0];
  const float* td = (const float*)d_in[1];
  const float* tf = (const float*)d_in[2];
  const float* mk = (const float*)d_in[3];
  const float* mv = (const float*)d_in[4];
  const float* mr = (const float*)d_in[5];
  const float* Wk = (const float*)d_in[6];
  const float* Wv = (const float*)d_in[7];
  const float* Wr = (const float*)d_in[8];
  const float* Wo = (const float*)d_in[9];
  float* out = (float*)d_out;           // output f32 (reference dtype)

  // ws: 3 bf16 [M,D] buffers (phased) + 4 partial arrays = exactly 100 MiB (proven fit)
  char* ws = (char*)d_ws;
  const size_t S2 = (size_t)M * Dd * sizeof(bf16);   // 33,554,432 B
  const size_t SP = (size_t)Bb * NC * Dd;            // 262,144 elems
  bf16* buf1 = (bf16*)(ws);              // xmk -> v -> y
  bf16* buf2 = (bf16*)(ws + S2);         // xmv -> xmr
  bf16* buf3 = (bf16*)(ws + 2 * S2);     // k (bf16)
  float* Pa = (float*)(ws + 3 * S2);
  float* Pb = Pa + SP;
  float* A0 = Pb + SP;
  float* B0 = A0 + SP;
  bf16* rr = (bf16*)d_out;               // sigmoid(r) parks in d_out; dead before final GEMM

  dim3 gp((unsigned)((size_t)M * Dd / (256 * 8)));   // 8192 blocks
  dim3 gg(Dd / 128, M / 128);                        // (8, 128)

  prep2<<<gp, 256, 0, stream>>>(x, mk, mv, buf1, buf2);          // xmk, xmv
  gemm_a16<2><<<gg, 256, 0, stream>>>(buf1, Wk, buf3);           // k  (bf16)  buf1 dead
  gemm_a16<2><<<gg, 256, 0, stream>>>(buf2, Wv, buf1);           // v  (bf16)  buf2 dead
  prep1<<<gp, 256, 0, stream>>>(x, mr, buf2);                    // xmr
  gemm_a16<1><<<gg, 256, 0, stream>>>(buf2, Wr, rr);             // sigmoid(r) -> d_out

  scan_partial<<<dim3(Dd / 256, Bb, NC), 256, 0, stream>>>(buf3, buf1, td, Pa, Pb);
  scan_combine<<<dim3(Dd / 256, Bb), 256, 0, stream>>>(td, Pa, Pb, A0, B0);
  scan_final  <<<dim3(Dd / 256, Bb, NC), 256, 0, stream>>>(buf3, buf1, rr, td, tf, A0, B0);

  gemm_a16<0><<<gg, 256, 0, stream>>>(buf1, Wo, out);            // y·Wo -> d_out (f32)
}